// Round 5
// baseline (25.312 us; speedup 1.0000x reference)
//
#include <hip/hip_runtime.h>
#include <math.h>

#define BLK 256

typedef float f32x4 __attribute__((ext_vector_type(4)));  // clang vector: valid for __builtin_nontemporal_store

// Brill-Lindquist Christoffel symbols, analytic form.
// psi = 1 + sum_i m_i/(2 r_i),  G = psi^4 I  =>  G^{-1} = psi^-4 I.
// C^k_ij = delta_ik q_j + delta_jk q_i - delta_ij q_k,  q_k = 2 (d_k psi)/psi.
// Phase 1 materializes each point's 27-value row into LDS (compile-time
// pattern, 27-dword lane stride: gcd(27,32)=1 -> 2-way bank aliasing, free).
// Phase 2 is an identity LDS->global copy (ds_read_b128 + dwordx4 stores),
// with NONTEMPORAL stores: the output is write-once, never re-read by the
// kernel, so bypassing L2/L3 allocation keeps the write stream draining at
// fill rate instead of churning the 256MB L3.
__global__ __launch_bounds__(BLK) void bl_christoffel_kernel(
    const float* __restrict__ x,        // [B,3]
    const float* __restrict__ masses,   // [2]
    const float* __restrict__ centers,  // [2,3]
    float* __restrict__ out,            // [B,3,3,3]
    int B)
{
    __shared__ float tile[BLK * 27];    // 27648 B: block's output image

    const int tid   = threadIdx.x;
    const int bbase = blockIdx.x * BLK;
    const int b     = bbase + tid;

    const float m0h = 0.5f * masses[0];
    const float m1h = 0.5f * masses[1];
    const float c00 = centers[0], c01 = centers[1], c02 = centers[2];
    const float c10 = centers[3], c11 = centers[4], c12 = centers[5];

    if (b < B) {
        const float x0 = x[3 * b + 0];
        const float x1 = x[3 * b + 1];
        const float x2 = x[3 * b + 2];

        const float d00 = x0 - c00, d01 = x1 - c01, d02 = x2 - c02;
        const float d10 = x0 - c10, d11 = x1 - c11, d12 = x2 - c12;

        const float ir0 = rsqrtf(d00 * d00 + d01 * d01 + d02 * d02);
        const float ir1 = rsqrtf(d10 * d10 + d11 * d11 + d12 * d12);

        const float psi = 1.0f + m0h * ir0 + m1h * ir1;
        const float a0  = m0h * ir0 * ir0 * ir0;   // m0/(2 r0^3)
        const float a1  = m1h * ir1 * ir1 * ir1;   // m1/(2 r1^3)
        const float s   = -2.0f / psi;             // q = 2 grad(psi)/psi

        const float q0 = s * (a0 * d00 + a1 * d10);
        const float q1 = s * (a0 * d01 + a1 * d11);
        const float q2 = s * (a0 * d02 + a1 * d12);
        const float n0 = -q0, n1 = -q1, n2 = -q2;

        float* lp = &tile[tid * 27];
        // c = k*9 + i*3 + j
        lp[ 0] = q0; lp[ 1] = q1; lp[ 2] = q2;   // k=0, i=0
        lp[ 3] = q1; lp[ 4] = n0; lp[ 5] = 0.f;  //      i=1
        lp[ 6] = q2; lp[ 7] = 0.f; lp[ 8] = n0;  //      i=2
        lp[ 9] = n1; lp[10] = q0; lp[11] = 0.f;  // k=1, i=0
        lp[12] = q0; lp[13] = q1; lp[14] = q2;   //      i=1
        lp[15] = 0.f; lp[16] = q2; lp[17] = n1;  //      i=2
        lp[18] = n2; lp[19] = 0.f; lp[20] = q0;  // k=2, i=0
        lp[21] = 0.f; lp[22] = n2; lp[23] = q1;  //      i=1
        lp[24] = q0; lp[25] = q1; lp[26] = q2;   //      i=2
    }

    __syncthreads();

    const int npts = min(BLK, B - bbase);
    float* o = out + (size_t)bbase * 27;

    if (npts == BLK) {
        // Identity copy: 6912 floats = 1728 float4 = 6.75 per thread.
        const f32x4* lsrc = (const f32x4*)tile;
        f32x4* o4 = (f32x4*)o;
#pragma unroll
        for (int n = 0; n < 6; ++n) {
            const int s4 = n * BLK + tid;
            __builtin_nontemporal_store(lsrc[s4], &o4[s4]);
        }
        const int s4 = 6 * BLK + tid;
        if (s4 < BLK * 27 / 4)
            __builtin_nontemporal_store(lsrc[s4], &o4[s4]);
    } else {
        const int total = npts * 27;
        for (int s = tid; s < total; s += BLK)
            __builtin_nontemporal_store(tile[s], &o[s]);
    }
}

extern "C" void kernel_launch(void* const* d_in, const int* in_sizes, int n_in,
                              void* d_out, int out_size, void* d_ws, size_t ws_size,
                              hipStream_t stream) {
    const float* x       = (const float*)d_in[0];
    const float* masses  = (const float*)d_in[1];
    const float* centers = (const float*)d_in[2];
    float* out           = (float*)d_out;

    const int B = in_sizes[0] / 3;
    const int grid = (B + BLK - 1) / BLK;

    bl_christoffel_kernel<<<grid, BLK, 0, stream>>>(x, masses, centers, out, B);
}

// Round 6
// 24.832 us; speedup vs baseline: 1.0193x; 1.0193x over previous
//
#include <hip/hip_runtime.h>
#include <math.h>

#define BLK  256
#define HALF 128

typedef float f32x4 __attribute__((ext_vector_type(4)));

// Brill-Lindquist Christoffel symbols, analytic form.
// psi = 1 + sum_i m_i/(2 r_i),  G = psi^4 I  =>  G^{-1} = psi^-4 I.
// C^k_ij = delta_ik q_j + delta_jk q_i - delta_ij q_k,  q_k = 2 (d_k psi)/psi.
// Phase 1: each thread computes its point's (q0,q1,q2) in registers.
// Phase 2: materialize + drain the block's output in TWO 128-point
// half-tiles (LDS 13824 B instead of 27648 B) -> 8 blocks/CU instead of 5,
// 32 waves/CU = 100% occupancy, more in-flight stores for the write stream.
// Drain is an identity LDS->global copy: ds_read_b128 + global_store_dwordx4,
// zero index math, perfectly coalesced.
__global__ __launch_bounds__(BLK) void bl_christoffel_kernel(
    const float* __restrict__ x,        // [B,3]
    const float* __restrict__ masses,   // [2]
    const float* __restrict__ centers,  // [2,3]
    float* __restrict__ out,            // [B,3,3,3]
    int B)
{
    __shared__ float tile[HALF * 27];   // 13824 B

    const int tid   = threadIdx.x;
    const int bbase = blockIdx.x * BLK;
    const int b     = bbase + tid;

    const float m0h = 0.5f * masses[0];
    const float m1h = 0.5f * masses[1];
    const float c00 = centers[0], c01 = centers[1], c02 = centers[2];
    const float c10 = centers[3], c11 = centers[4], c12 = centers[5];

    float q0 = 0.f, q1 = 0.f, q2 = 0.f;
    if (b < B) {
        const float x0 = x[3 * b + 0];
        const float x1 = x[3 * b + 1];
        const float x2 = x[3 * b + 2];

        const float d00 = x0 - c00, d01 = x1 - c01, d02 = x2 - c02;
        const float d10 = x0 - c10, d11 = x1 - c11, d12 = x2 - c12;

        const float ir0 = rsqrtf(d00 * d00 + d01 * d01 + d02 * d02);
        const float ir1 = rsqrtf(d10 * d10 + d11 * d11 + d12 * d12);

        const float psi = 1.0f + m0h * ir0 + m1h * ir1;
        const float a0  = m0h * ir0 * ir0 * ir0;   // m0/(2 r0^3)
        const float a1  = m1h * ir1 * ir1 * ir1;   // m1/(2 r1^3)
        const float s   = -2.0f / psi;             // q = 2 grad(psi)/psi

        q0 = s * (a0 * d00 + a1 * d10);
        q1 = s * (a0 * d01 + a1 * d11);
        q2 = s * (a0 * d02 + a1 * d12);
    }
    const float n0 = -q0, n1 = -q1, n2 = -q2;

#pragma unroll
    for (int h = 0; h < 2; ++h) {
        if ((tid >> 7) == h) {
            float* lp = &tile[(tid & (HALF - 1)) * 27];
            // c = k*9 + i*3 + j
            lp[ 0] = q0; lp[ 1] = q1; lp[ 2] = q2;   // k=0, i=0
            lp[ 3] = q1; lp[ 4] = n0; lp[ 5] = 0.f;  //      i=1
            lp[ 6] = q2; lp[ 7] = 0.f; lp[ 8] = n0;  //      i=2
            lp[ 9] = n1; lp[10] = q0; lp[11] = 0.f;  // k=1, i=0
            lp[12] = q0; lp[13] = q1; lp[14] = q2;   //      i=1
            lp[15] = 0.f; lp[16] = q2; lp[17] = n1;  //      i=2
            lp[18] = n2; lp[19] = 0.f; lp[20] = q0;  // k=2, i=0
            lp[21] = 0.f; lp[22] = n2; lp[23] = q1;  //      i=1
            lp[24] = q0; lp[25] = q1; lp[26] = q2;   //      i=2
        }
        __syncthreads();

        const int base = bbase + h * HALF;
        const int npts = min(HALF, B - base);
        float* o = out + (size_t)base * 27;

        if (npts == HALF) {
            // Identity copy: 3456 floats = 864 float4, 256 threads.
            const f32x4* lsrc = (const f32x4*)tile;
            f32x4* o4 = (f32x4*)o;
#pragma unroll
            for (int n = 0; n < 3; ++n) {
                const int s4 = n * BLK + tid;
                o4[s4] = lsrc[s4];
            }
            const int s4 = 3 * BLK + tid;
            if (s4 < HALF * 27 / 4) o4[s4] = lsrc[s4];
        } else if (npts > 0) {
            const int total = npts * 27;
            for (int s = tid; s < total; s += BLK) o[s] = tile[s];
        }

        if (h == 0) __syncthreads();   // tile reused by second half
    }
}

extern "C" void kernel_launch(void* const* d_in, const int* in_sizes, int n_in,
                              void* d_out, int out_size, void* d_ws, size_t ws_size,
                              hipStream_t stream) {
    const float* x       = (const float*)d_in[0];
    const float* masses  = (const float*)d_in[1];
    const float* centers = (const float*)d_in[2];
    float* out           = (float*)d_out;

    const int B = in_sizes[0] / 3;
    const int grid = (B + BLK - 1) / BLK;

    bl_christoffel_kernel<<<grid, BLK, 0, stream>>>(x, masses, centers, out, B);
}